// Round 12
// baseline (471.670 us; speedup 1.0000x reference)
//
#include <hip/hip_runtime.h>
#include <math.h>

#define NN   100000
#define EE   1600000
#define ET   (EE + NN)          // edges + self-loops = 1,700,000
#define HID  64
#define MLPH 128
#define ODIM 74
#define SLOPE 0.2f

#define NB   196                // coarse buckets of 512 nodes (dst >> 9)
#define GA   800                // pass-A blocks
#define EPB  (EE / GA)          // 2000 edges per pass-A block

__device__ __forceinline__ float f4get(const float4& v, int i) {
    return i == 0 ? v.x : i == 1 ? v.y : i == 2 ? v.z : v.w;  // unrolled -> constant
}
// bf16 round-to-nearest-even pack/unpack
__device__ __forceinline__ unsigned short f2bf(float f) {
    unsigned u = __float_as_uint(f);
    u += 0x7fffu + ((u >> 16) & 1u);
    return (unsigned short)(u >> 16);
}
__device__ __forceinline__ float bf2f(unsigned short s) {
    return __uint_as_float(((unsigned)s) << 16);
}

// ================= CSR build: bucketed counting sort, no global atomics =================

__global__ void k_partA_hist(const int* __restrict__ edst, int* __restrict__ M) {
    __shared__ int hist[NB];
    int t = threadIdx.x;
    if (t < NB) hist[t] = 0;
    __syncthreads();
    int base = blockIdx.x * EPB;
    for (int i = t; i < EPB; i += 256)
        atomicAdd(&hist[edst[base + i] >> 9], 1);
    __syncthreads();
    if (t < NB) M[blockIdx.x * NB + t] = hist[t];
}

__global__ void k_scan_col(const int* __restrict__ M, int* __restrict__ colExcl,
                           int* __restrict__ colsum) {
    __shared__ int sd[256];
    __shared__ int carry;
    int k = blockIdx.x, t = threadIdx.x;
    if (t == 0) carry = 0;
    __syncthreads();
    for (int c = 0; c < GA; c += 256) {
        int v = (c + t < GA) ? M[(c + t) * NB + k] : 0;
        sd[t] = v;
        __syncthreads();
        for (int o = 1; o < 256; o <<= 1) {
            int u = (t >= o) ? sd[t - o] : 0;
            __syncthreads();
            sd[t] += u;
            __syncthreads();
        }
        if (c + t < GA) colExcl[(c + t) * NB + k] = carry + sd[t] - v;
        __syncthreads();
        if (t == 255) carry += sd[255];
        __syncthreads();
    }
    if (t == 0) colsum[k] = carry;
}

__global__ void k_scan_bkt(const int* __restrict__ colsum, int* __restrict__ bucketBase) {
    __shared__ int sd[256];
    int t = threadIdx.x;
    int v = (t < NB) ? colsum[t] : 0;
    sd[t] = v;
    __syncthreads();
    for (int o = 1; o < 256; o <<= 1) {
        int u = (t >= o) ? sd[t - o] : 0;
        __syncthreads();
        sd[t] += u;
        __syncthreads();
    }
    if (t < NB) bucketBase[t] = sd[t] - v;
    if (t == NB - 1) bucketBase[NB] = sd[t];
}

__global__ void k_partA_scat(const int* __restrict__ esrc, const int* __restrict__ edst,
                             const int* __restrict__ colExcl, const int* __restrict__ bucketBase,
                             unsigned long long* __restrict__ tmp) {
    __shared__ int cur[NB];
    int t = threadIdx.x;
    if (t < NB) cur[t] = bucketBase[t] + colExcl[blockIdx.x * NB + t];
    __syncthreads();
    int base = blockIdx.x * EPB;
    for (int i = t; i < EPB; i += 256) {
        int s = esrc[base + i], d = edst[base + i];
        int pos = atomicAdd(&cur[d >> 9], 1);
        tmp[pos] = ((unsigned long long)(unsigned)d << 32) | (unsigned)s;
    }
}

__global__ __launch_bounds__(512) void k_partB(
        const unsigned long long* __restrict__ tmp, const int* __restrict__ bucketBase,
        int* __restrict__ rowbeg, int* __restrict__ rowend, int* __restrict__ col) {
    __shared__ int deg[512];
    __shared__ int rb[512];
    __shared__ int cur[512];
    int k = blockIdx.x, t = threadIdx.x;
    int lo = bucketBase[k], hi = bucketBase[k + 1];
    int nodeBase = k << 9;
    int nNodes = (NN - nodeBase < 512) ? (NN - nodeBase) : 512;

    deg[t] = 0;
    __syncthreads();
    for (int i = lo + t; i < hi; i += 512)
        atomicAdd(&deg[(int)(tmp[i] >> 32) - nodeBase], 1);
    __syncthreads();

    int v = (t < nNodes) ? deg[t] + 1 : 0;
    rb[t] = v;
    __syncthreads();
    for (int o = 1; o < 512; o <<= 1) {
        int u = (t >= o) ? rb[t - o] : 0;
        __syncthreads();
        rb[t] += u;
        __syncthreads();
    }
    int myBeg = lo + nodeBase + rb[t] - v;
    if (t < nNodes) {
        int g = nodeBase + t;
        rowbeg[g] = myBeg;
        rowend[g] = myBeg + deg[t] + 1;
        col[myBeg] = g;              // self-loop first in row
        cur[t] = myBeg + 1;
    }
    __syncthreads();
    for (int i = lo + t; i < hi; i += 512) {
        unsigned long long e = tmp[i];
        int dLow = (int)(e >> 32) - nodeBase;
        int pos = atomicAdd(&cur[dLow], 1);
        col[pos] = (int)(e & 0xffffffffu);
    }
}

// transpose+pad Wp2 -> Wp2T[96][128] (rows >= ODIM are zero)
__global__ void k_transW(const float* __restrict__ Wp2, float* __restrict__ wT) {
    int i = blockIdx.x * 256 + threadIdx.x;
    if (i >= 96 * 128) return;
    int o = i >> 7, j = i & 127;
    wT[i] = (o < ODIM) ? Wp2[j * ODIM + o] : 0.f;
}

// ---------------- dense prologues (h stored as bf16) ----------------

__global__ void k_lin1(const float* __restrict__ x, const float* __restrict__ W,
                       const float* __restrict__ asrc, const float* __restrict__ adst,
                       unsigned short* __restrict__ h16,
                       float* __restrict__ hs, float* __restrict__ hd) {
    int node = blockIdx.x * 4 + (threadIdx.x >> 6);
    int f    = threadIdx.x & 63;
    float x0 = x[node*3+0], x1 = x[node*3+1], x2 = x[node*3+2];
    float v  = x0*W[f] + x1*W[64+f] + x2*W[128+f];
    h16[node*64+f] = f2bf(v);
    float ps = v*asrc[f], pd = v*adst[f];
    #pragma unroll
    for (int o = 32; o > 0; o >>= 1) { ps += __shfl_down(ps, o); pd += __shfl_down(pd, o); }
    if (f == 0) { hs[node] = ps; hd[node] = pd; }
}

__global__ __launch_bounds__(128) void k_lin64(
        const float* __restrict__ xin, const float* __restrict__ W,
        const float* __restrict__ asrc, const float* __restrict__ adst,
        unsigned short* __restrict__ h16,
        float* __restrict__ hs, float* __restrict__ hd) {
    __shared__ __align__(16) float xr[32][64];     // 8 KB (x rows, later reused for h rows)
    __shared__ __align__(16) float wl[64*64];      // 16 KB, [k][o] layout
    int t  = threadIdx.x;
    int nb = blockIdx.x * 32;
    for (int i = t; i < 32*64; i += 128) xr[i >> 6][i & 63] = xin[nb*64 + i];
    for (int i = t; i < 64*64;  i += 128) wl[i] = W[i];
    __syncthreads();

    int nq = t >> 4;    // 0..7 (4 nodes each)
    int hq = t & 15;    // 0..15 (4 outs each)
    float acc[4][4] = {};
    #pragma unroll 4
    for (int k = 0; k < 64; k += 4) {
        float4 xv[4];
        #pragma unroll
        for (int ni = 0; ni < 4; ++ni) xv[ni] = *(const float4*)&xr[nq*4+ni][k];
        #pragma unroll
        for (int kk = 0; kk < 4; ++kk) {
            float4 wv = *(const float4*)&wl[(k+kk)*64 + hq*4];
            #pragma unroll
            for (int ni = 0; ni < 4; ++ni) {
                float xs = f4get(xv[ni], kk);
                acc[ni][0] += xs*wv.x; acc[ni][1] += xs*wv.y;
                acc[ni][2] += xs*wv.z; acc[ni][3] += xs*wv.w;
            }
        }
    }
    float4 res[4];
    #pragma unroll
    for (int ni = 0; ni < 4; ++ni) {
        res[ni] = make_float4(acc[ni][0], acc[ni][1], acc[ni][2], acc[ni][3]);
        ushort4 u4;
        u4.x = f2bf(res[ni].x); u4.y = f2bf(res[ni].y);
        u4.z = f2bf(res[ni].z); u4.w = f2bf(res[ni].w);
        *(ushort4*)&h16[(size_t)(nb + nq*4 + ni)*64 + hq*4] = u4;
    }
    __syncthreads();
    #pragma unroll
    for (int ni = 0; ni < 4; ++ni) *(float4*)&xr[nq*4+ni][hq*4] = res[ni];
    __syncthreads();

    int wv_  = t >> 6;
    int lane = t & 63;
    for (int ni = 0; ni < 16; ++ni) {
        int node = wv_*16 + ni;
        float v  = xr[node][lane];
        float ps = v*asrc[lane], pd = v*adst[lane];
        #pragma unroll
        for (int o = 32; o > 0; o >>= 1) { ps += __shfl_down(ps, o); pd += __shfl_down(pd, o); }
        if (lane == 0) { hs[nb+node] = ps; hd[nb+node] = pd; }
    }
}

// ---------------- fused GAT aggregate v3: bf16 h gather (half the bytes) ----------------
__global__ void k_gat(const int* __restrict__ rowbeg, const int* __restrict__ rowend,
                      const int* __restrict__ col,
                      const float* __restrict__ hs, const float* __restrict__ hd,
                      const unsigned short* __restrict__ h16, const float* __restrict__ bias,
                      float* __restrict__ out) {
    __shared__ float se[4][128];
    __shared__ int   sc[4][128];
    int w    = threadIdx.x >> 6;
    int lane = threadIdx.x & 63;
    int n    = blockIdx.x * 4 + w;
    float* e_ = se[w];
    int*   c_ = sc[w];

    int base = rowbeg[n];
    int d    = rowend[n] - base;          // >=1 (self-loop)
    float hdn = hd[n];

    // phase A1: scores (+ stash col) + wave max
    float mymax = -INFINITY;
    for (int k = lane; k < d; k += 64) {
        int s = col[base + k];
        float scv = hs[s] + hdn;
        scv = (scv > 0.f) ? scv : SLOPE * scv;
        if (k < 128) { e_[k] = scv; c_[k] = s; }
        mymax = fmaxf(mymax, scv);
    }
    #pragma unroll
    for (int o = 32; o > 0; o >>= 1) mymax = fmaxf(mymax, __shfl_xor(mymax, o));

    // phase A2: exp + wave sum
    float mysum = 0.f;
    for (int k = lane; k < d; k += 64) {
        float scv;
        if (k < 128) scv = e_[k];
        else {
            int s = col[base + k];
            scv = hs[s] + hdn;
            scv = (scv > 0.f) ? scv : SLOPE * scv;
        }
        float p = expf(scv - mymax);
        if (k < 128) e_[k] = p;
        mysum += p;
    }
    #pragma unroll
    for (int o = 32; o > 0; o >>= 1) mysum += __shfl_xor(mysum, o);
    float inv = 1.f / mysum;

    __syncthreads();   // publish p/col for cross-lane reads

    // phase B: 4 edges at a time; lane = (g: edge subgroup, q: 4-feature slot); bf16 rows
    int g = lane >> 4;        // edge subgroup 0..3
    int q = lane & 15;        // features q*4..q*4+3
    int dl = (d < 128) ? d : 128;
    float4 acc4 = make_float4(0.f, 0.f, 0.f, 0.f);
    int k = g;
    for (; k + 4 < dl; k += 8) {
        float p0 = e_[k];     int s0 = c_[k];
        float p1 = e_[k+4];   int s1 = c_[k+4];
        ushort4 u0 = *(const ushort4*)&h16[(size_t)s0*64 + q*4];
        ushort4 u1 = *(const ushort4*)&h16[(size_t)s1*64 + q*4];
        acc4.x += p0*bf2f(u0.x) + p1*bf2f(u1.x);
        acc4.y += p0*bf2f(u0.y) + p1*bf2f(u1.y);
        acc4.z += p0*bf2f(u0.z) + p1*bf2f(u1.z);
        acc4.w += p0*bf2f(u0.w) + p1*bf2f(u1.w);
    }
    if (k < dl) {
        float p0 = e_[k];     int s0 = c_[k];
        ushort4 u0 = *(const ushort4*)&h16[(size_t)s0*64 + q*4];
        acc4.x += p0*bf2f(u0.x); acc4.y += p0*bf2f(u0.y);
        acc4.z += p0*bf2f(u0.z); acc4.w += p0*bf2f(u0.w);
    }
    for (int kk = 128 + g; kk < d; kk += 4) {   // d>128 spill path
        int s = col[base + kk];
        float scv = hs[s] + hdn;
        scv = (scv > 0.f) ? scv : SLOPE * scv;
        float p = expf(scv - mymax);
        ushort4 u0 = *(const ushort4*)&h16[(size_t)s*64 + q*4];
        acc4.x += p*bf2f(u0.x); acc4.y += p*bf2f(u0.y);
        acc4.z += p*bf2f(u0.z); acc4.w += p*bf2f(u0.w);
    }
    #pragma unroll
    for (int o = 16; o <= 32; o <<= 1) {
        acc4.x += __shfl_xor(acc4.x, o);
        acc4.y += __shfl_xor(acc4.y, o);
        acc4.z += __shfl_xor(acc4.z, o);
        acc4.w += __shfl_xor(acc4.w, o);
    }
    if (g == 0) {
        float4 bv = *(const float4*)&bias[q*4];
        float4 r;
        r.x = fmaxf(acc4.x*inv + bv.x, 0.f);
        r.y = fmaxf(acc4.y*inv + bv.y, 0.f);
        r.z = fmaxf(acc4.z*inv + bv.z, 0.f);
        r.w = fmaxf(acc4.w*inv + bv.w, 0.f);
        *(float4*)&out[(size_t)n*64 + q*4] = r;
    }
}

// ---------------- MLP head v7: phase-2 via transposed Wp2T (f4 weight loads) ----------------
__global__ __launch_bounds__(256) void k_mlp(
        const float* __restrict__ xin,
        const float* __restrict__ Wp1, const float* __restrict__ bp1,
        const float* __restrict__ wT, const float* __restrict__ bp2,
        float* __restrict__ out) {
    __shared__ __align__(16) float xr[32][64];     // 8 KB
    __shared__ __align__(16) float hid[32][132];   // 16.9 KB; stride 132 = 33x16B
    int t  = threadIdx.x;
    int nb = blockIdx.x * 32;
    int nq = t >> 5;      // 0..7  (4 nodes each)
    int hq = t & 31;      // 0..31

    for (int i = t; i < 32*64; i += 256) xr[i >> 6][i & 63] = xin[(size_t)nb*64 + i];
    __syncthreads();

    // phase 1: hid = relu(x @ Wp1 + bp1) — v5 form (f4 LDS + f4 global, unroll 2)
    {
        float4 bv = *(const float4*)&bp1[hq*4];
        float acc[4][4];
        #pragma unroll
        for (int ni = 0; ni < 4; ++ni) {
            acc[ni][0] = bv.x; acc[ni][1] = bv.y; acc[ni][2] = bv.z; acc[ni][3] = bv.w;
        }
        #pragma unroll 2
        for (int k = 0; k < 64; k += 4) {
            float4 xv[4];
            #pragma unroll
            for (int ni = 0; ni < 4; ++ni) xv[ni] = *(const float4*)&xr[nq*4+ni][k];
            #pragma unroll
            for (int kk = 0; kk < 4; ++kk) {
                float4 wv = *(const float4*)&Wp1[(k+kk)*MLPH + hq*4];
                #pragma unroll
                for (int ni = 0; ni < 4; ++ni) {
                    float xs = f4get(xv[ni], kk);
                    acc[ni][0] += xs*wv.x; acc[ni][1] += xs*wv.y;
                    acc[ni][2] += xs*wv.z; acc[ni][3] += xs*wv.w;
                }
            }
        }
        #pragma unroll
        for (int ni = 0; ni < 4; ++ni)
            *(float4*)&hid[nq*4+ni][hq*4] = make_float4(
                fmaxf(acc[ni][0], 0.f), fmaxf(acc[ni][1], 0.f),
                fmaxf(acc[ni][2], 0.f), fmaxf(acc[ni][3], 0.f));
    }
    __syncthreads();

    // phase 2: out = hid @ Wp2 + bp2 via Wp2T rows (contiguous f4 loads)
    {
        int oq = t & 31;
        bool has3 = (oq + 64) < ODIM;   // oq < 10
        float a0[4], a1[4], a2[4];
        float b0 = bp2[oq], b1v = bp2[oq+32], b2v = has3 ? bp2[oq+64] : 0.f;
        #pragma unroll
        for (int ni = 0; ni < 4; ++ni) { a0[ni] = b0; a1[ni] = b1v; a2[ni] = b2v; }
        const float* w0p = &wT[(size_t)oq * 128];
        const float* w1p = &wT[(size_t)(oq+32) * 128];
        const float* w2p = &wT[(size_t)(oq+64) * 128];   // zero rows past 73
        #pragma unroll 2
        for (int j = 0; j < MLPH; j += 4) {
            float4 w0 = *(const float4*)&w0p[j];
            float4 w1 = *(const float4*)&w1p[j];
            float4 w2 = *(const float4*)&w2p[j];
            float4 hv[4];
            #pragma unroll
            for (int ni = 0; ni < 4; ++ni) hv[ni] = *(const float4*)&hid[nq*4+ni][j];
            #pragma unroll
            for (int jj = 0; jj < 4; ++jj) {
                float ww0 = f4get(w0, jj), ww1 = f4get(w1, jj), ww2 = f4get(w2, jj);
                #pragma unroll
                for (int ni = 0; ni < 4; ++ni) {
                    float hx = f4get(hv[ni], jj);
                    a0[ni] += hx*ww0; a1[ni] += hx*ww1; a2[ni] += hx*ww2;
                }
            }
        }
        #pragma unroll
        for (int ni = 0; ni < 4; ++ni) {
            size_t rowo = (size_t)(nb + nq*4 + ni) * ODIM;
            out[rowo + oq]      = a0[ni];
            out[rowo + oq + 32] = a1[ni];
            if (has3) out[rowo + oq + 64] = a2[ni];
        }
    }
}

// ---------------- launch ----------------

extern "C" void kernel_launch(void* const* d_in, const int* in_sizes, int n_in,
                              void* d_out, int out_size, void* d_ws, size_t ws_size,
                              hipStream_t stream) {
    const float* x    = (const float*)d_in[0];
    const int*   ei   = (const int*)  d_in[1];
    const float* W1   = (const float*)d_in[2];
    const float* a1s  = (const float*)d_in[3];
    const float* a1d  = (const float*)d_in[4];
    const float* b1   = (const float*)d_in[5];
    const float* W2   = (const float*)d_in[6];
    const float* a2s  = (const float*)d_in[7];
    const float* a2d  = (const float*)d_in[8];
    const float* b2   = (const float*)d_in[9];
    const float* Wp1  = (const float*)d_in[10];
    const float* bp1  = (const float*)d_in[11];
    const float* Wp2  = (const float*)d_in[12];
    const float* bp2  = (const float*)d_in[13];
    float* out = (float*)d_out;

    const int* esrc = ei;
    const int* edst = ei + EE;

    float* ws   = (float*)d_ws;
    float* bufA = ws;                      // h region; first 12.8MB overlaid by tmp during CSR build
    float* bufB = bufA + NN*HID;           // layer outputs (N*64 fp32)
    float* wT   = bufB + NN*HID;           // 96*128 transposed/padded Wp2 (16B-aligned)
    float* hs   = wT + 96*128;             // N
    float* hd   = hs + NN;                 // N
    int* rowbeg = (int*)(hd + NN);         // N
    int* rowend = rowbeg + NN;             // N
    int* col    = rowend + NN;             // ET
    int* M      = col + ET;                // GA*NB
    int* colExcl= M + GA*NB;               // GA*NB
    int* colsum = colExcl + GA*NB;         // NB
    int* bucketBase = colsum + NB;         // NB+1
    unsigned long long* tmp = (unsigned long long*)bufA;   // EE packed records (12.8MB)
    unsigned short* h16 = (unsigned short*)bufA;           // bf16 h (12.8MB), written after tmp consumed

    // ---- CSR build (no global atomics; shared by both layers) + weight transpose ----
    k_partA_hist<<<GA, 256, 0, stream>>>(edst, M);
    k_scan_col  <<<NB, 256, 0, stream>>>(M, colExcl, colsum);
    k_scan_bkt  <<<1, 256, 0, stream>>>(colsum, bucketBase);
    k_partA_scat<<<GA, 256, 0, stream>>>(esrc, edst, colExcl, bucketBase, tmp);
    k_partB     <<<NB, 512, 0, stream>>>(tmp, bucketBase, rowbeg, rowend, col);
    k_transW    <<<48, 256, 0, stream>>>(Wp2, wT);

    // ---- GAT layer 1 (k_lin1 writes h16 over bufA after tmp is consumed; stream-ordered) ----
    k_lin1<<<NN/4, 256, 0, stream>>>(x, W1, a1s, a1d, h16, hs, hd);
    k_gat <<<NN/4, 256, 0, stream>>>(rowbeg, rowend, col, hs, hd, h16, b1, bufB);

    // ---- GAT layer 2 ----
    k_lin64<<<NN/32, 128, 0, stream>>>(bufB, W2, a2s, a2d, h16, hs, hd);
    k_gat  <<<NN/4, 256, 0, stream>>>(rowbeg, rowend, col, hs, hd, h16, b2, bufB);

    // ---- MLP head ----
    k_mlp<<<NN/32, 256, 0, stream>>>(bufB, Wp1, bp1, wT, bp2, out);
}

// Round 13
// 376.989 us; speedup vs baseline: 1.2512x; 1.2512x over previous
//
#include <hip/hip_runtime.h>
#include <math.h>

#define NN   100000
#define EE   1600000
#define ET   (EE + NN)          // edges + self-loops = 1,700,000
#define HID  64
#define MLPH 128
#define ODIM 74
#define SLOPE 0.2f

#define NB   196                // coarse buckets of 512 nodes (dst >> 9)
#define GA   800                // pass-A blocks
#define EPB  (EE / GA)          // 2000 edges per pass-A block

__device__ __forceinline__ float f4get(const float4& v, int i) {
    return i == 0 ? v.x : i == 1 ? v.y : i == 2 ? v.z : v.w;  // unrolled -> constant
}
// bf16 round-to-nearest-even pack/unpack
__device__ __forceinline__ unsigned short f2bf(float f) {
    unsigned u = __float_as_uint(f);
    u += 0x7fffu + ((u >> 16) & 1u);
    return (unsigned short)(u >> 16);
}
__device__ __forceinline__ float bf2f(unsigned short s) {
    return __uint_as_float(((unsigned)s) << 16);
}

// ================= CSR build: bucketed counting sort, no global atomics =================

__global__ void k_partA_hist(const int* __restrict__ edst, int* __restrict__ M) {
    __shared__ int hist[NB];
    int t = threadIdx.x;
    if (t < NB) hist[t] = 0;
    __syncthreads();
    int base = blockIdx.x * EPB;
    for (int i = t; i < EPB; i += 256)
        atomicAdd(&hist[edst[base + i] >> 9], 1);
    __syncthreads();
    if (t < NB) M[blockIdx.x * NB + t] = hist[t];
}

__global__ void k_scan_col(const int* __restrict__ M, int* __restrict__ colExcl,
                           int* __restrict__ colsum) {
    __shared__ int sd[256];
    __shared__ int carry;
    int k = blockIdx.x, t = threadIdx.x;
    if (t == 0) carry = 0;
    __syncthreads();
    for (int c = 0; c < GA; c += 256) {
        int v = (c + t < GA) ? M[(c + t) * NB + k] : 0;
        sd[t] = v;
        __syncthreads();
        for (int o = 1; o < 256; o <<= 1) {
            int u = (t >= o) ? sd[t - o] : 0;
            __syncthreads();
            sd[t] += u;
            __syncthreads();
        }
        if (c + t < GA) colExcl[(c + t) * NB + k] = carry + sd[t] - v;
        __syncthreads();
        if (t == 255) carry += sd[255];
        __syncthreads();
    }
    if (t == 0) colsum[k] = carry;
}

__global__ void k_scan_bkt(const int* __restrict__ colsum, int* __restrict__ bucketBase) {
    __shared__ int sd[256];
    int t = threadIdx.x;
    int v = (t < NB) ? colsum[t] : 0;
    sd[t] = v;
    __syncthreads();
    for (int o = 1; o < 256; o <<= 1) {
        int u = (t >= o) ? sd[t - o] : 0;
        __syncthreads();
        sd[t] += u;
        __syncthreads();
    }
    if (t < NB) bucketBase[t] = sd[t] - v;
    if (t == NB - 1) bucketBase[NB] = sd[t];
}

__global__ void k_partA_scat(const int* __restrict__ esrc, const int* __restrict__ edst,
                             const int* __restrict__ colExcl, const int* __restrict__ bucketBase,
                             unsigned long long* __restrict__ tmp) {
    __shared__ int cur[NB];
    int t = threadIdx.x;
    if (t < NB) cur[t] = bucketBase[t] + colExcl[blockIdx.x * NB + t];
    __syncthreads();
    int base = blockIdx.x * EPB;
    for (int i = t; i < EPB; i += 256) {
        int s = esrc[base + i], d = edst[base + i];
        int pos = atomicAdd(&cur[d >> 9], 1);
        tmp[pos] = ((unsigned long long)(unsigned)d << 32) | (unsigned)s;
    }
}

__global__ __launch_bounds__(512) void k_partB(
        const unsigned long long* __restrict__ tmp, const int* __restrict__ bucketBase,
        int* __restrict__ rowbeg, int* __restrict__ rowend, int* __restrict__ col) {
    __shared__ int deg[512];
    __shared__ int rb[512];
    __shared__ int cur[512];
    int k = blockIdx.x, t = threadIdx.x;
    int lo = bucketBase[k], hi = bucketBase[k + 1];
    int nodeBase = k << 9;
    int nNodes = (NN - nodeBase < 512) ? (NN - nodeBase) : 512;

    deg[t] = 0;
    __syncthreads();
    for (int i = lo + t; i < hi; i += 512)
        atomicAdd(&deg[(int)(tmp[i] >> 32) - nodeBase], 1);
    __syncthreads();

    int v = (t < nNodes) ? deg[t] + 1 : 0;
    rb[t] = v;
    __syncthreads();
    for (int o = 1; o < 512; o <<= 1) {
        int u = (t >= o) ? rb[t - o] : 0;
        __syncthreads();
        rb[t] += u;
        __syncthreads();
    }
    int myBeg = lo + nodeBase + rb[t] - v;
    if (t < nNodes) {
        int g = nodeBase + t;
        rowbeg[g] = myBeg;
        rowend[g] = myBeg + deg[t] + 1;
        col[myBeg] = g;              // self-loop first in row
        cur[t] = myBeg + 1;
    }
    __syncthreads();
    for (int i = lo + t; i < hi; i += 512) {
        unsigned long long e = tmp[i];
        int dLow = (int)(e >> 32) - nodeBase;
        int pos = atomicAdd(&cur[dLow], 1);
        col[pos] = (int)(e & 0xffffffffu);
    }
}

// ---------------- dense prologues (h stored as bf16) ----------------

__global__ void k_lin1(const float* __restrict__ x, const float* __restrict__ W,
                       const float* __restrict__ asrc, const float* __restrict__ adst,
                       unsigned short* __restrict__ h16,
                       float* __restrict__ hs, float* __restrict__ hd) {
    int node = blockIdx.x * 4 + (threadIdx.x >> 6);
    int f    = threadIdx.x & 63;
    float x0 = x[node*3+0], x1 = x[node*3+1], x2 = x[node*3+2];
    float v  = x0*W[f] + x1*W[64+f] + x2*W[128+f];
    h16[node*64+f] = f2bf(v);
    float ps = v*asrc[f], pd = v*adst[f];
    #pragma unroll
    for (int o = 32; o > 0; o >>= 1) { ps += __shfl_down(ps, o); pd += __shfl_down(pd, o); }
    if (f == 0) { hs[node] = ps; hd[node] = pd; }
}

__global__ __launch_bounds__(128) void k_lin64(
        const float* __restrict__ xin, const float* __restrict__ W,
        const float* __restrict__ asrc, const float* __restrict__ adst,
        unsigned short* __restrict__ h16,
        float* __restrict__ hs, float* __restrict__ hd) {
    __shared__ __align__(16) float xr[32][64];     // 8 KB (x rows, later reused for h rows)
    __shared__ __align__(16) float wl[64*64];      // 16 KB, [k][o] layout
    int t  = threadIdx.x;
    int nb = blockIdx.x * 32;
    for (int i = t; i < 32*64; i += 128) xr[i >> 6][i & 63] = xin[nb*64 + i];
    for (int i = t; i < 64*64;  i += 128) wl[i] = W[i];
    __syncthreads();

    int nq = t >> 4;    // 0..7 (4 nodes each)
    int hq = t & 15;    // 0..15 (4 outs each)
    float acc[4][4] = {};
    #pragma unroll 4
    for (int k = 0; k < 64; k += 4) {
        float4 xv[4];
        #pragma unroll
        for (int ni = 0; ni < 4; ++ni) xv[ni] = *(const float4*)&xr[nq*4+ni][k];
        #pragma unroll
        for (int kk = 0; kk < 4; ++kk) {
            float4 wv = *(const float4*)&wl[(k+kk)*64 + hq*4];
            #pragma unroll
            for (int ni = 0; ni < 4; ++ni) {
                float xs = f4get(xv[ni], kk);
                acc[ni][0] += xs*wv.x; acc[ni][1] += xs*wv.y;
                acc[ni][2] += xs*wv.z; acc[ni][3] += xs*wv.w;
            }
        }
    }
    float4 res[4];
    #pragma unroll
    for (int ni = 0; ni < 4; ++ni) {
        res[ni] = make_float4(acc[ni][0], acc[ni][1], acc[ni][2], acc[ni][3]);
        ushort4 u4;
        u4.x = f2bf(res[ni].x); u4.y = f2bf(res[ni].y);
        u4.z = f2bf(res[ni].z); u4.w = f2bf(res[ni].w);
        *(ushort4*)&h16[(size_t)(nb + nq*4 + ni)*64 + hq*4] = u4;
    }
    __syncthreads();
    #pragma unroll
    for (int ni = 0; ni < 4; ++ni) *(float4*)&xr[nq*4+ni][hq*4] = res[ni];
    __syncthreads();

    int wv_  = t >> 6;
    int lane = t & 63;
    for (int ni = 0; ni < 16; ++ni) {
        int node = wv_*16 + ni;
        float v  = xr[node][lane];
        float ps = v*asrc[lane], pd = v*adst[lane];
        #pragma unroll
        for (int o = 32; o > 0; o >>= 1) { ps += __shfl_down(ps, o); pd += __shfl_down(pd, o); }
        if (lane == 0) { hs[nb+node] = ps; hd[nb+node] = pd; }
    }
}

// ---------------- fused GAT aggregate v3: bf16 h gather (half the bytes) ----------------
__global__ void k_gat(const int* __restrict__ rowbeg, const int* __restrict__ rowend,
                      const int* __restrict__ col,
                      const float* __restrict__ hs, const float* __restrict__ hd,
                      const unsigned short* __restrict__ h16, const float* __restrict__ bias,
                      float* __restrict__ out) {
    __shared__ float se[4][128];
    __shared__ int   sc[4][128];
    int w    = threadIdx.x >> 6;
    int lane = threadIdx.x & 63;
    int n    = blockIdx.x * 4 + w;
    float* e_ = se[w];
    int*   c_ = sc[w];

    int base = rowbeg[n];
    int d    = rowend[n] - base;          // >=1 (self-loop)
    float hdn = hd[n];

    // phase A1: scores (+ stash col) + wave max
    float mymax = -INFINITY;
    for (int k = lane; k < d; k += 64) {
        int s = col[base + k];
        float scv = hs[s] + hdn;
        scv = (scv > 0.f) ? scv : SLOPE * scv;
        if (k < 128) { e_[k] = scv; c_[k] = s; }
        mymax = fmaxf(mymax, scv);
    }
    #pragma unroll
    for (int o = 32; o > 0; o >>= 1) mymax = fmaxf(mymax, __shfl_xor(mymax, o));

    // phase A2: exp + wave sum
    float mysum = 0.f;
    for (int k = lane; k < d; k += 64) {
        float scv;
        if (k < 128) scv = e_[k];
        else {
            int s = col[base + k];
            scv = hs[s] + hdn;
            scv = (scv > 0.f) ? scv : SLOPE * scv;
        }
        float p = expf(scv - mymax);
        if (k < 128) e_[k] = p;
        mysum += p;
    }
    #pragma unroll
    for (int o = 32; o > 0; o >>= 1) mysum += __shfl_xor(mysum, o);
    float inv = 1.f / mysum;

    __syncthreads();   // publish p/col for cross-lane reads

    // phase B: 4 edges at a time; lane = (g: edge subgroup, q: 4-feature slot); bf16 rows
    int g = lane >> 4;        // edge subgroup 0..3
    int q = lane & 15;        // features q*4..q*4+3
    int dl = (d < 128) ? d : 128;
    float4 acc4 = make_float4(0.f, 0.f, 0.f, 0.f);
    int k = g;
    for (; k + 4 < dl; k += 8) {
        float p0 = e_[k];     int s0 = c_[k];
        float p1 = e_[k+4];   int s1 = c_[k+4];
        ushort4 u0 = *(const ushort4*)&h16[(size_t)s0*64 + q*4];
        ushort4 u1 = *(const ushort4*)&h16[(size_t)s1*64 + q*4];
        acc4.x += p0*bf2f(u0.x) + p1*bf2f(u1.x);
        acc4.y += p0*bf2f(u0.y) + p1*bf2f(u1.y);
        acc4.z += p0*bf2f(u0.z) + p1*bf2f(u1.z);
        acc4.w += p0*bf2f(u0.w) + p1*bf2f(u1.w);
    }
    if (k < dl) {
        float p0 = e_[k];     int s0 = c_[k];
        ushort4 u0 = *(const ushort4*)&h16[(size_t)s0*64 + q*4];
        acc4.x += p0*bf2f(u0.x); acc4.y += p0*bf2f(u0.y);
        acc4.z += p0*bf2f(u0.z); acc4.w += p0*bf2f(u0.w);
    }
    for (int kk = 128 + g; kk < d; kk += 4) {   // d>128 spill path
        int s = col[base + kk];
        float scv = hs[s] + hdn;
        scv = (scv > 0.f) ? scv : SLOPE * scv;
        float p = expf(scv - mymax);
        ushort4 u0 = *(const ushort4*)&h16[(size_t)s*64 + q*4];
        acc4.x += p*bf2f(u0.x); acc4.y += p*bf2f(u0.y);
        acc4.z += p*bf2f(u0.z); acc4.w += p*bf2f(u0.w);
    }
    #pragma unroll
    for (int o = 16; o <= 32; o <<= 1) {
        acc4.x += __shfl_xor(acc4.x, o);
        acc4.y += __shfl_xor(acc4.y, o);
        acc4.z += __shfl_xor(acc4.z, o);
        acc4.w += __shfl_xor(acc4.w, o);
    }
    if (g == 0) {
        float4 bv = *(const float4*)&bias[q*4];
        float4 r;
        r.x = fmaxf(acc4.x*inv + bv.x, 0.f);
        r.y = fmaxf(acc4.y*inv + bv.y, 0.f);
        r.z = fmaxf(acc4.z*inv + bv.z, 0.f);
        r.w = fmaxf(acc4.w*inv + bv.w, 0.f);
        *(float4*)&out[(size_t)n*64 + q*4] = r;
    }
}

// ---------------- MLP head v8: = v5 (lane-coalesced Wp2 scalar loads) ----------------
// v7 lesson: per-thread-contiguous wT rows destroyed INTER-LANE coalescing (each f4
// load touched 32 cache lines) -> 183us. Coalescing is across lanes: Wp2[j*ODIM+oq]
// with consecutive oq is one 128B segment per instruction. Revert to that form.
__global__ __launch_bounds__(256) void k_mlp(
        const float* __restrict__ xin,
        const float* __restrict__ Wp1, const float* __restrict__ bp1,
        const float* __restrict__ Wp2, const float* __restrict__ bp2,
        float* __restrict__ out) {
    __shared__ __align__(16) float xr[32][64];     // 8 KB
    __shared__ __align__(16) float hid[32][132];   // 16.9 KB; stride 132 = 33x16B
    int t  = threadIdx.x;
    int nb = blockIdx.x * 32;
    int nq = t >> 5;      // 0..7  (4 nodes each)
    int hq = t & 31;      // 0..31

    for (int i = t; i < 32*64; i += 256) xr[i >> 6][i & 63] = xin[(size_t)nb*64 + i];
    __syncthreads();

    // phase 1: hid = relu(x @ Wp1 + bp1); f4 LDS + f4 global (coalesced), unroll 2
    {
        float4 bv = *(const float4*)&bp1[hq*4];
        float acc[4][4];
        #pragma unroll
        for (int ni = 0; ni < 4; ++ni) {
            acc[ni][0] = bv.x; acc[ni][1] = bv.y; acc[ni][2] = bv.z; acc[ni][3] = bv.w;
        }
        #pragma unroll 2
        for (int k = 0; k < 64; k += 4) {
            float4 xv[4];
            #pragma unroll
            for (int ni = 0; ni < 4; ++ni) xv[ni] = *(const float4*)&xr[nq*4+ni][k];
            #pragma unroll
            for (int kk = 0; kk < 4; ++kk) {
                float4 wv = *(const float4*)&Wp1[(k+kk)*MLPH + hq*4];
                #pragma unroll
                for (int ni = 0; ni < 4; ++ni) {
                    float xs = f4get(xv[ni], kk);
                    acc[ni][0] += xs*wv.x; acc[ni][1] += xs*wv.y;
                    acc[ni][2] += xs*wv.z; acc[ni][3] += xs*wv.w;
                }
            }
        }
        #pragma unroll
        for (int ni = 0; ni < 4; ++ni)
            *(float4*)&hid[nq*4+ni][hq*4] = make_float4(
                fmaxf(acc[ni][0], 0.f), fmaxf(acc[ni][1], 0.f),
                fmaxf(acc[ni][2], 0.f), fmaxf(acc[ni][3], 0.f));
    }
    __syncthreads();

    // phase 2: out = hid @ Wp2 + bp2; lane-coalesced scalar weight loads
    {
        int oq = t & 31;
        bool has3 = (oq + 64) < ODIM;   // oq < 10
        float a0[4], a1[4], a2[4];
        float b0 = bp2[oq], b1v = bp2[oq+32], b2v = has3 ? bp2[oq+64] : 0.f;
        #pragma unroll
        for (int ni = 0; ni < 4; ++ni) { a0[ni] = b0; a1[ni] = b1v; a2[ni] = b2v; }
        #pragma unroll 2
        for (int j = 0; j < MLPH; j += 4) {
            float4 hv[4];
            #pragma unroll
            for (int ni = 0; ni < 4; ++ni) hv[ni] = *(const float4*)&hid[nq*4+ni][j];
            #pragma unroll
            for (int jj = 0; jj < 4; ++jj) {
                float w0 = Wp2[(j+jj)*ODIM + oq];
                float w1 = Wp2[(j+jj)*ODIM + oq + 32];
                float w2 = has3 ? Wp2[(j+jj)*ODIM + oq + 64] : 0.f;
                float h0 = f4get(hv[0], jj), h1 = f4get(hv[1], jj);
                float h2 = f4get(hv[2], jj), h3 = f4get(hv[3], jj);
                a0[0] += h0*w0; a1[0] += h0*w1; a2[0] += h0*w2;
                a0[1] += h1*w0; a1[1] += h1*w1; a2[1] += h1*w2;
                a0[2] += h2*w0; a1[2] += h2*w1; a2[2] += h2*w2;
                a0[3] += h3*w0; a1[3] += h3*w1; a2[3] += h3*w2;
            }
        }
        #pragma unroll
        for (int ni = 0; ni < 4; ++ni) {
            size_t rowo = (size_t)(nb + nq*4 + ni) * ODIM;
            out[rowo + oq]      = a0[ni];
            out[rowo + oq + 32] = a1[ni];
            if (has3) out[rowo + oq + 64] = a2[ni];
        }
    }
}

// ---------------- launch ----------------

extern "C" void kernel_launch(void* const* d_in, const int* in_sizes, int n_in,
                              void* d_out, int out_size, void* d_ws, size_t ws_size,
                              hipStream_t stream) {
    const float* x    = (const float*)d_in[0];
    const int*   ei   = (const int*)  d_in[1];
    const float* W1   = (const float*)d_in[2];
    const float* a1s  = (const float*)d_in[3];
    const float* a1d  = (const float*)d_in[4];
    const float* b1   = (const float*)d_in[5];
    const float* W2   = (const float*)d_in[6];
    const float* a2s  = (const float*)d_in[7];
    const float* a2d  = (const float*)d_in[8];
    const float* b2   = (const float*)d_in[9];
    const float* Wp1  = (const float*)d_in[10];
    const float* bp1  = (const float*)d_in[11];
    const float* Wp2  = (const float*)d_in[12];
    const float* bp2  = (const float*)d_in[13];
    float* out = (float*)d_out;

    const int* esrc = ei;
    const int* edst = ei + EE;

    float* ws   = (float*)d_ws;
    float* bufA = ws;                      // h region; first 12.8MB overlaid by tmp during CSR build
    float* bufB = bufA + NN*HID;           // layer outputs (N*64 fp32)
    float* hs   = bufB + NN*HID;           // N
    float* hd   = hs + NN;                 // N
    int* rowbeg = (int*)(hd + NN);         // N
    int* rowend = rowbeg + NN;             // N
    int* col    = rowend + NN;             // ET
    int* M      = col + ET;                // GA*NB
    int* colExcl= M + GA*NB;               // GA*NB
    int* colsum = colExcl + GA*NB;         // NB
    int* bucketBase = colsum + NB;         // NB+1
    unsigned long long* tmp = (unsigned long long*)bufA;   // EE packed records (12.8MB)
    unsigned short* h16 = (unsigned short*)bufA;           // bf16 h (12.8MB), written after tmp consumed

    // ---- CSR build (no global atomics; shared by both layers) ----
    k_partA_hist<<<GA, 256, 0, stream>>>(edst, M);
    k_scan_col  <<<NB, 256, 0, stream>>>(M, colExcl, colsum);
    k_scan_bkt  <<<1, 256, 0, stream>>>(colsum, bucketBase);
    k_partA_scat<<<GA, 256, 0, stream>>>(esrc, edst, colExcl, bucketBase, tmp);
    k_partB     <<<NB, 512, 0, stream>>>(tmp, bucketBase, rowbeg, rowend, col);

    // ---- GAT layer 1 (k_lin1 writes h16 over bufA after tmp is consumed; stream-ordered) ----
    k_lin1<<<NN/4, 256, 0, stream>>>(x, W1, a1s, a1d, h16, hs, hd);
    k_gat <<<NN/4, 256, 0, stream>>>(rowbeg, rowend, col, hs, hd, h16, b1, bufB);

    // ---- GAT layer 2 ----
    k_lin64<<<NN/32, 128, 0, stream>>>(bufB, W2, a2s, a2d, h16, hs, hd);
    k_gat  <<<NN/4, 256, 0, stream>>>(rowbeg, rowend, col, hs, hd, h16, b2, bufB);

    // ---- MLP head ----
    k_mlp<<<NN/32, 256, 0, stream>>>(bufB, Wp1, bp1, Wp2, bp2, out);
}

// Round 14
// 320.716 us; speedup vs baseline: 1.4707x; 1.1755x over previous
//
#include <hip/hip_runtime.h>
#include <math.h>

#define NN   100000
#define EE   1600000
#define ET   (EE + NN)          // edges + self-loops = 1,700,000
#define HID  64
#define MLPH 128
#define ODIM 74
#define SLOPE 0.2f

#define NB   196                // coarse buckets of 512 nodes (dst >> 9)
#define GA   800                // pass-A blocks
#define EPB  (EE / GA)          // 2000 edges per pass-A block

typedef __attribute__((ext_vector_type(8))) short bf16x8;   // 8 bf16 in 4 VGPRs
typedef __attribute__((ext_vector_type(4))) float f32x4;

__device__ __forceinline__ float f4get(const float4& v, int i) {
    return i == 0 ? v.x : i == 1 ? v.y : i == 2 ? v.z : v.w;  // unrolled -> constant
}
// bf16 round-to-nearest-even pack/unpack
__device__ __forceinline__ unsigned short f2bf(float f) {
    unsigned u = __float_as_uint(f);
    u += 0x7fffu + ((u >> 16) & 1u);
    return (unsigned short)(u >> 16);
}
__device__ __forceinline__ float bf2f(unsigned short s) {
    return __uint_as_float(((unsigned)s) << 16);
}

// ================= CSR build: bucketed counting sort, no global atomics =================

__global__ void k_partA_hist(const int* __restrict__ edst, int* __restrict__ M) {
    __shared__ int hist[NB];
    int t = threadIdx.x;
    if (t < NB) hist[t] = 0;
    __syncthreads();
    int base = blockIdx.x * EPB;
    for (int i = t; i < EPB; i += 256)
        atomicAdd(&hist[edst[base + i] >> 9], 1);
    __syncthreads();
    if (t < NB) M[blockIdx.x * NB + t] = hist[t];
}

__global__ void k_scan_col(const int* __restrict__ M, int* __restrict__ colExcl,
                           int* __restrict__ colsum) {
    __shared__ int sd[256];
    __shared__ int carry;
    int k = blockIdx.x, t = threadIdx.x;
    if (t == 0) carry = 0;
    __syncthreads();
    for (int c = 0; c < GA; c += 256) {
        int v = (c + t < GA) ? M[(c + t) * NB + k] : 0;
        sd[t] = v;
        __syncthreads();
        for (int o = 1; o < 256; o <<= 1) {
            int u = (t >= o) ? sd[t - o] : 0;
            __syncthreads();
            sd[t] += u;
            __syncthreads();
        }
        if (c + t < GA) colExcl[(c + t) * NB + k] = carry + sd[t] - v;
        __syncthreads();
        if (t == 255) carry += sd[255];
        __syncthreads();
    }
    if (t == 0) colsum[k] = carry;
}

__global__ void k_scan_bkt(const int* __restrict__ colsum, int* __restrict__ bucketBase) {
    __shared__ int sd[256];
    int t = threadIdx.x;
    int v = (t < NB) ? colsum[t] : 0;
    sd[t] = v;
    __syncthreads();
    for (int o = 1; o < 256; o <<= 1) {
        int u = (t >= o) ? sd[t - o] : 0;
        __syncthreads();
        sd[t] += u;
        __syncthreads();
    }
    if (t < NB) bucketBase[t] = sd[t] - v;
    if (t == NB - 1) bucketBase[NB] = sd[t];
}

__global__ void k_partA_scat(const int* __restrict__ esrc, const int* __restrict__ edst,
                             const int* __restrict__ colExcl, const int* __restrict__ bucketBase,
                             unsigned long long* __restrict__ tmp) {
    __shared__ int cur[NB];
    int t = threadIdx.x;
    if (t < NB) cur[t] = bucketBase[t] + colExcl[blockIdx.x * NB + t];
    __syncthreads();
    int base = blockIdx.x * EPB;
    for (int i = t; i < EPB; i += 256) {
        int s = esrc[base + i], d = edst[base + i];
        int pos = atomicAdd(&cur[d >> 9], 1);
        tmp[pos] = ((unsigned long long)(unsigned)d << 32) | (unsigned)s;
    }
}

__global__ __launch_bounds__(512) void k_partB(
        const unsigned long long* __restrict__ tmp, const int* __restrict__ bucketBase,
        int* __restrict__ rowbeg, int* __restrict__ rowend, int* __restrict__ col) {
    __shared__ int deg[512];
    __shared__ int rb[512];
    __shared__ int cur[512];
    int k = blockIdx.x, t = threadIdx.x;
    int lo = bucketBase[k], hi = bucketBase[k + 1];
    int nodeBase = k << 9;
    int nNodes = (NN - nodeBase < 512) ? (NN - nodeBase) : 512;

    deg[t] = 0;
    __syncthreads();
    for (int i = lo + t; i < hi; i += 512)
        atomicAdd(&deg[(int)(tmp[i] >> 32) - nodeBase], 1);
    __syncthreads();

    int v = (t < nNodes) ? deg[t] + 1 : 0;
    rb[t] = v;
    __syncthreads();
    for (int o = 1; o < 512; o <<= 1) {
        int u = (t >= o) ? rb[t - o] : 0;
        __syncthreads();
        rb[t] += u;
        __syncthreads();
    }
    int myBeg = lo + nodeBase + rb[t] - v;
    if (t < nNodes) {
        int g = nodeBase + t;
        rowbeg[g] = myBeg;
        rowend[g] = myBeg + deg[t] + 1;
        col[myBeg] = g;              // self-loop first in row
        cur[t] = myBeg + 1;
    }
    __syncthreads();
    for (int i = lo + t; i < hi; i += 512) {
        unsigned long long e = tmp[i];
        int dLow = (int)(e >> 32) - nodeBase;
        int pos = atomicAdd(&cur[dLow], 1);
        col[pos] = (int)(e & 0xffffffffu);
    }
}

// pack Wp1/Wp2 into bf16 MFMA B-fragment order: frag[(nt*KB+kb)][lane][e]
// lane l supplies B[k = kb*32 + (l>>4)*8 + e][n = nt*16 + (l&15)]
__global__ void k_prepw(const float* __restrict__ Wp1, const float* __restrict__ Wp2,
                        unsigned short* __restrict__ w1p, unsigned short* __restrict__ w2p) {
    int i = blockIdx.x * 256 + threadIdx.x;
    if (i < 8192) {   // 8 nt x 2 kb x 64 lanes x 8 e
        int e = i & 7, lane = (i >> 3) & 63, kb = (i >> 9) & 1, nt = i >> 10;
        int k = kb*32 + ((lane >> 4) << 3) + e, n = nt*16 + (lane & 15);
        w1p[i] = f2bf(Wp1[k*MLPH + n]);
    }
    if (i < 12288) {  // 6 nt x 4 kb x 64 x 8
        int e = i & 7, lane = (i >> 3) & 63, kb = (i >> 9) & 3, nt = i >> 11;
        int k = kb*32 + ((lane >> 4) << 3) + e, n = nt*16 + (lane & 15);
        w2p[i] = (n < ODIM) ? f2bf(Wp2[k*ODIM + n]) : (unsigned short)0;
    }
}

// ---------------- dense prologues (h stored as bf16) ----------------

__global__ void k_lin1(const float* __restrict__ x, const float* __restrict__ W,
                       const float* __restrict__ asrc, const float* __restrict__ adst,
                       unsigned short* __restrict__ h16,
                       float* __restrict__ hs, float* __restrict__ hd) {
    int node = blockIdx.x * 4 + (threadIdx.x >> 6);
    int f    = threadIdx.x & 63;
    float x0 = x[node*3+0], x1 = x[node*3+1], x2 = x[node*3+2];
    float v  = x0*W[f] + x1*W[64+f] + x2*W[128+f];
    h16[node*64+f] = f2bf(v);
    float ps = v*asrc[f], pd = v*adst[f];
    #pragma unroll
    for (int o = 32; o > 0; o >>= 1) { ps += __shfl_down(ps, o); pd += __shfl_down(pd, o); }
    if (f == 0) { hs[node] = ps; hd[node] = pd; }
}

__global__ __launch_bounds__(128) void k_lin64(
        const float* __restrict__ xin, const float* __restrict__ W,
        const float* __restrict__ asrc, const float* __restrict__ adst,
        unsigned short* __restrict__ h16,
        float* __restrict__ hs, float* __restrict__ hd) {
    __shared__ __align__(16) float xr[32][64];     // 8 KB (x rows, later reused for h rows)
    __shared__ __align__(16) float wl[64*64];      // 16 KB, [k][o] layout
    int t  = threadIdx.x;
    int nb = blockIdx.x * 32;
    for (int i = t; i < 32*64; i += 128) xr[i >> 6][i & 63] = xin[nb*64 + i];
    for (int i = t; i < 64*64;  i += 128) wl[i] = W[i];
    __syncthreads();

    int nq = t >> 4;    // 0..7 (4 nodes each)
    int hq = t & 15;    // 0..15 (4 outs each)
    float acc[4][4] = {};
    #pragma unroll 4
    for (int k = 0; k < 64; k += 4) {
        float4 xv[4];
        #pragma unroll
        for (int ni = 0; ni < 4; ++ni) xv[ni] = *(const float4*)&xr[nq*4+ni][k];
        #pragma unroll
        for (int kk = 0; kk < 4; ++kk) {
            float4 wv = *(const float4*)&wl[(k+kk)*64 + hq*4];
            #pragma unroll
            for (int ni = 0; ni < 4; ++ni) {
                float xs = f4get(xv[ni], kk);
                acc[ni][0] += xs*wv.x; acc[ni][1] += xs*wv.y;
                acc[ni][2] += xs*wv.z; acc[ni][3] += xs*wv.w;
            }
        }
    }
    float4 res[4];
    #pragma unroll
    for (int ni = 0; ni < 4; ++ni) {
        res[ni] = make_float4(acc[ni][0], acc[ni][1], acc[ni][2], acc[ni][3]);
        ushort4 u4;
        u4.x = f2bf(res[ni].x); u4.y = f2bf(res[ni].y);
        u4.z = f2bf(res[ni].z); u4.w = f2bf(res[ni].w);
        *(ushort4*)&h16[(size_t)(nb + nq*4 + ni)*64 + hq*4] = u4;
    }
    __syncthreads();
    #pragma unroll
    for (int ni = 0; ni < 4; ++ni) *(float4*)&xr[nq*4+ni][hq*4] = res[ni];
    __syncthreads();

    int wv_  = t >> 6;
    int lane = t & 63;
    for (int ni = 0; ni < 16; ++ni) {
        int node = wv_*16 + ni;
        float v  = xr[node][lane];
        float ps = v*asrc[lane], pd = v*adst[lane];
        #pragma unroll
        for (int o = 32; o > 0; o >>= 1) { ps += __shfl_down(ps, o); pd += __shfl_down(pd, o); }
        if (lane == 0) { hs[nb+node] = ps; hd[nb+node] = pd; }
    }
}

// ---------------- fused GAT aggregate v3: bf16 h gather ----------------
__global__ void k_gat(const int* __restrict__ rowbeg, const int* __restrict__ rowend,
                      const int* __restrict__ col,
                      const float* __restrict__ hs, const float* __restrict__ hd,
                      const unsigned short* __restrict__ h16, const float* __restrict__ bias,
                      float* __restrict__ out) {
    __shared__ float se[4][128];
    __shared__ int   sc[4][128];
    int w    = threadIdx.x >> 6;
    int lane = threadIdx.x & 63;
    int n    = blockIdx.x * 4 + w;
    float* e_ = se[w];
    int*   c_ = sc[w];

    int base = rowbeg[n];
    int d    = rowend[n] - base;          // >=1 (self-loop)
    float hdn = hd[n];

    // phase A1: scores (+ stash col) + wave max
    float mymax = -INFINITY;
    for (int k = lane; k < d; k += 64) {
        int s = col[base + k];
        float scv = hs[s] + hdn;
        scv = (scv > 0.f) ? scv : SLOPE * scv;
        if (k < 128) { e_[k] = scv; c_[k] = s; }
        mymax = fmaxf(mymax, scv);
    }
    #pragma unroll
    for (int o = 32; o > 0; o >>= 1) mymax = fmaxf(mymax, __shfl_xor(mymax, o));

    // phase A2: exp + wave sum
    float mysum = 0.f;
    for (int k = lane; k < d; k += 64) {
        float scv;
        if (k < 128) scv = e_[k];
        else {
            int s = col[base + k];
            scv = hs[s] + hdn;
            scv = (scv > 0.f) ? scv : SLOPE * scv;
        }
        float p = expf(scv - mymax);
        if (k < 128) e_[k] = p;
        mysum += p;
    }
    #pragma unroll
    for (int o = 32; o > 0; o >>= 1) mysum += __shfl_xor(mysum, o);
    float inv = 1.f / mysum;

    __syncthreads();   // publish p/col for cross-lane reads

    // phase B: 4 edges at a time; lane = (g: edge subgroup, q: 4-feature slot); bf16 rows
    int g = lane >> 4;        // edge subgroup 0..3
    int q = lane & 15;        // features q*4..q*4+3
    int dl = (d < 128) ? d : 128;
    float4 acc4 = make_float4(0.f, 0.f, 0.f, 0.f);
    int k = g;
    for (; k + 4 < dl; k += 8) {
        float p0 = e_[k];     int s0 = c_[k];
        float p1 = e_[k+4];   int s1 = c_[k+4];
        ushort4 u0 = *(const ushort4*)&h16[(size_t)s0*64 + q*4];
        ushort4 u1 = *(const ushort4*)&h16[(size_t)s1*64 + q*4];
        acc4.x += p0*bf2f(u0.x) + p1*bf2f(u1.x);
        acc4.y += p0*bf2f(u0.y) + p1*bf2f(u1.y);
        acc4.z += p0*bf2f(u0.z) + p1*bf2f(u1.z);
        acc4.w += p0*bf2f(u0.w) + p1*bf2f(u1.w);
    }
    if (k < dl) {
        float p0 = e_[k];     int s0 = c_[k];
        ushort4 u0 = *(const ushort4*)&h16[(size_t)s0*64 + q*4];
        acc4.x += p0*bf2f(u0.x); acc4.y += p0*bf2f(u0.y);
        acc4.z += p0*bf2f(u0.z); acc4.w += p0*bf2f(u0.w);
    }
    for (int kk = 128 + g; kk < d; kk += 4) {   // d>128 spill path
        int s = col[base + kk];
        float scv = hs[s] + hdn;
        scv = (scv > 0.f) ? scv : SLOPE * scv;
        float p = expf(scv - mymax);
        ushort4 u0 = *(const ushort4*)&h16[(size_t)s*64 + q*4];
        acc4.x += p*bf2f(u0.x); acc4.y += p*bf2f(u0.y);
        acc4.z += p*bf2f(u0.z); acc4.w += p*bf2f(u0.w);
    }
    #pragma unroll
    for (int o = 16; o <= 32; o <<= 1) {
        acc4.x += __shfl_xor(acc4.x, o);
        acc4.y += __shfl_xor(acc4.y, o);
        acc4.z += __shfl_xor(acc4.z, o);
        acc4.w += __shfl_xor(acc4.w, o);
    }
    if (g == 0) {
        float4 bv = *(const float4*)&bias[q*4];
        float4 r;
        r.x = fmaxf(acc4.x*inv + bv.x, 0.f);
        r.y = fmaxf(acc4.y*inv + bv.y, 0.f);
        r.z = fmaxf(acc4.z*inv + bv.z, 0.f);
        r.w = fmaxf(acc4.w*inv + bv.w, 0.f);
        *(float4*)&out[(size_t)n*64 + q*4] = r;
    }
}

// ---------------- MLP head v9: MFMA (bf16) ----------------
// 32 nodes/block, 4 waves. Phase1: hid[32x128] = x[32x64] @ Wp1; 16x16x32 MFMA,
// wave w: mt=w>>1, nt=(w&1)*4..+3, 2 K-steps. Phase2: out[32x96pad] = hid @ Wp2,
// wave w: mt=w>>1, nt=(w&1)*3..+2, 4 K-steps. B-frags preswizzled by k_prepw ->
// one coalesced 16B load each. C/D layout (m89-verified): col=lane&15, row=(lane>>4)*4+reg.
// LDS rows padded to 72/136 ushorts: 16B-aligned b128 reads, 2-way banks (free).
__global__ __launch_bounds__(256) void k_mlp(
        const float* __restrict__ xin,
        const unsigned short* __restrict__ w1p, const float* __restrict__ bp1,
        const unsigned short* __restrict__ w2p, const float* __restrict__ bp2,
        float* __restrict__ out) {
    __shared__ __align__(16) unsigned short x16[32][72];    // 4.5 KB
    __shared__ __align__(16) unsigned short hid16[32][136]; // 8.5 KB
    int t  = threadIdx.x;
    int nb = blockIdx.x * 32;

    // stage x -> bf16 LDS (each thread: 8 elems of one row)
    {
        int r = t >> 3, c = (t & 7) * 8;
        float4 v0 = *(const float4*)&xin[(size_t)(nb + r)*64 + c];
        float4 v1 = *(const float4*)&xin[(size_t)(nb + r)*64 + c + 4];
        ushort4 u0, u1;
        u0.x = f2bf(v0.x); u0.y = f2bf(v0.y); u0.z = f2bf(v0.z); u0.w = f2bf(v0.w);
        u1.x = f2bf(v1.x); u1.y = f2bf(v1.y); u1.z = f2bf(v1.z); u1.w = f2bf(v1.w);
        *(ushort4*)&x16[r][c]     = u0;
        *(ushort4*)&x16[r][c + 4] = u1;
    }
    __syncthreads();

    int w = t >> 6, lane = t & 63;
    int lrow = lane & 15;            // A row / D col
    int lk   = (lane >> 4) * 8;      // k-offset within 32
    int lr4  = (lane >> 4) * 4;      // D row base

    // phase 1: hid = relu(x @ Wp1 + bp1)
    {
        int mt  = w >> 1;
        int ntb = (w & 1) * 4;
        bf16x8 a0 = *(const bf16x8*)&x16[mt*16 + lrow][lk];
        bf16x8 a1 = *(const bf16x8*)&x16[mt*16 + lrow][32 + lk];
        #pragma unroll
        for (int j = 0; j < 4; ++j) {
            int nt = ntb + j;
            float bv = bp1[nt*16 + lrow];
            f32x4 acc = { bv, bv, bv, bv };
            bf16x8 b0 = *(const bf16x8*)&w1p[(size_t)((nt*2 + 0)*64 + lane)*8];
            bf16x8 b1 = *(const bf16x8*)&w1p[(size_t)((nt*2 + 1)*64 + lane)*8];
            acc = __builtin_amdgcn_mfma_f32_16x16x32_bf16(a0, b0, acc, 0, 0, 0);
            acc = __builtin_amdgcn_mfma_f32_16x16x32_bf16(a1, b1, acc, 0, 0, 0);
            #pragma unroll
            for (int r = 0; r < 4; ++r)
                hid16[mt*16 + lr4 + r][nt*16 + lrow] = f2bf(fmaxf(acc[r], 0.f));
        }
    }
    __syncthreads();

    // phase 2: out = hid @ Wp2 + bp2 (N padded to 96; cols >= 74 skipped)
    {
        int mt  = w >> 1;
        int ntb = (w & 1) * 3;
        bf16x8 a[4];
        #pragma unroll
        for (int kb = 0; kb < 4; ++kb)
            a[kb] = *(const bf16x8*)&hid16[mt*16 + lrow][kb*32 + lk];
        #pragma unroll
        for (int j = 0; j < 3; ++j) {
            int nt = ntb + j;
            int n  = nt*16 + lrow;
            float bv = (n < ODIM) ? bp2[n] : 0.f;
            f32x4 acc = { bv, bv, bv, bv };
            #pragma unroll
            for (int kb = 0; kb < 4; ++kb) {
                bf16x8 b = *(const bf16x8*)&w2p[(size_t)((nt*4 + kb)*64 + lane)*8];
                acc = __builtin_amdgcn_mfma_f32_16x16x32_bf16(a[kb], b, acc, 0, 0, 0);
            }
            if (n < ODIM) {
                #pragma unroll
                for (int r = 0; r < 4; ++r)
                    out[(size_t)(nb + mt*16 + lr4 + r)*ODIM + n] = acc[r];
            }
        }
    }
}

// ---------------- launch ----------------

extern "C" void kernel_launch(void* const* d_in, const int* in_sizes, int n_in,
                              void* d_out, int out_size, void* d_ws, size_t ws_size,
                              hipStream_t stream) {
    const float* x    = (const float*)d_in[0];
    const int*   ei   = (const int*)  d_in[1];
    const float* W1   = (const float*)d_in[2];
    const float* a1s  = (const float*)d_in[3];
    const float* a1d  = (const float*)d_in[4];
    const float* b1   = (const float*)d_in[5];
    const float* W2   = (const float*)d_in[6];
    const float* a2s  = (const float*)d_in[7];
    const float* a2d  = (const float*)d_in[8];
    const float* b2   = (const float*)d_in[9];
    const float* Wp1  = (const float*)d_in[10];
    const float* bp1  = (const float*)d_in[11];
    const float* Wp2  = (const float*)d_in[12];
    const float* bp2  = (const float*)d_in[13];
    float* out = (float*)d_out;

    const int* esrc = ei;
    const int* edst = ei + EE;

    float* ws   = (float*)d_ws;
    float* bufA = ws;                      // h region; first 13.6MB overlaid by tmp during CSR build
    float* bufB = bufA + NN*HID;           // layer outputs (N*64 fp32)
    float* hs   = bufB + NN*HID;           // N
    float* hd   = hs + NN;                 // N
    int* rowbeg = (int*)(hd + NN);         // N
    int* rowend = rowbeg + NN;             // N
    int* col    = rowend + NN;             // ET
    int* M      = col + ET;                // GA*NB
    int* colExcl= M + GA*NB;               // GA*NB
    int* colsum = colExcl + GA*NB;         // NB
    int* bucketBase = colsum + NB;         // NB+1
    unsigned short* w1p = (unsigned short*)(bucketBase + 200);  // 8192  (16B-aligned)
    unsigned short* w2p = w1p + 8192;                           // 12288
    unsigned long long* tmp = (unsigned long long*)bufA;   // EE packed records (12.8MB)
    unsigned short* h16 = (unsigned short*)bufA;           // bf16 h (12.8MB), written after tmp consumed

    // ---- CSR build (no global atomics; shared by both layers) + weight prep ----
    k_partA_hist<<<GA, 256, 0, stream>>>(edst, M);
    k_scan_col  <<<NB, 256, 0, stream>>>(M, colExcl, colsum);
    k_scan_bkt  <<<1, 256, 0, stream>>>(colsum, bucketBase);
    k_partA_scat<<<GA, 256, 0, stream>>>(esrc, edst, colExcl, bucketBase, tmp);
    k_partB     <<<NB, 512, 0, stream>>>(tmp, bucketBase, rowbeg, rowend, col);
    k_prepw     <<<48, 256, 0, stream>>>(Wp1, Wp2, w1p, w2p);

    // ---- GAT layer 1 (k_lin1 writes h16 over bufA after tmp is consumed; stream-ordered) ----
    k_lin1<<<NN/4, 256, 0, stream>>>(x, W1, a1s, a1d, h16, hs, hd);
    k_gat <<<NN/4, 256, 0, stream>>>(rowbeg, rowend, col, hs, hd, h16, b1, bufB);

    // ---- GAT layer 2 ----
    k_lin64<<<NN/32, 128, 0, stream>>>(bufB, W2, a2s, a2d, h16, hs, hd);
    k_gat  <<<NN/4, 256, 0, stream>>>(rowbeg, rowend, col, hs, hd, h16, b2, bufB);

    // ---- MLP head (MFMA) ----
    k_mlp<<<NN/32, 256, 0, stream>>>(bufB, w1p, bp1, w2p, bp2, out);
}